// Round 3
// baseline (1058.363 us; speedup 1.0000x reference)
//
#include <hip/hip_runtime.h>
#include <math.h>

#define TOKENS 16384
#define DIM    4096
#define NEXP   64
#define BT     256     // tokens per block
#define BK     16      // k per stage
#define LSTR   20      // LDS row stride (floats): 16B-aligned, spreads rows over all bank-quads

// ---------------- GEMM partial: scores[t][e] partial over a K-slice ----------------
// grid = (TOKENS/BT) * ksplit, block = 256. Thread tile 8 tok x 8 exp, strided.
__global__ __launch_bounds__(256, 2)
void gemm_partial(const float* __restrict__ x, const float* __restrict__ W,
                  float* __restrict__ part, int nstep)
{
    __shared__ float xs [2][BT][LSTR];     // 40 KB
    __shared__ float wsh[2][NEXP][LSTR];   // 10 KB

    const int tid   = threadIdx.x;
    const int tg    = blockIdx.x & 63;          // token group (TOKENS/BT = 64)
    const int ks    = blockIdx.x >> 6;          // K-slice id
    const int tb    = tg * BT;
    const int kbase = ks * nstep * BK;

    // staging map: 64 rows x 4 float4 per sweep (coalesced: 4 lanes cover 64B/row)
    const int srow = tid >> 2;                  // 0..63
    const int sc   = (tid & 3) << 2;            // 0,4,8,12

    // compute map: 32 token-threads x 8 expert-threads
    const int tr = tid >> 3;                    // 0..31 -> tokens tr+32i
    const int er = tid & 7;                     // 0..7  -> experts er+8j

    float acc[8][8];
#pragma unroll
    for (int i = 0; i < 8; ++i)
#pragma unroll
        for (int j = 0; j < 8; ++j) acc[i][j] = 0.f;

    // ---- prologue: stage step 0 into buf 0 ----
    {
        const int k0 = kbase;
        float4 gx0 = *(const float4*)&x[(size_t)(tb+srow      )*DIM + k0 + sc];
        float4 gx1 = *(const float4*)&x[(size_t)(tb+srow +  64)*DIM + k0 + sc];
        float4 gx2 = *(const float4*)&x[(size_t)(tb+srow + 128)*DIM + k0 + sc];
        float4 gx3 = *(const float4*)&x[(size_t)(tb+srow + 192)*DIM + k0 + sc];
        float4 gw0 = *(const float4*)&W[(size_t)srow*DIM + k0 + sc];
        *(float4*)&xs [0][srow      ][sc] = gx0;
        *(float4*)&xs [0][srow +  64][sc] = gx1;
        *(float4*)&xs [0][srow + 128][sc] = gx2;
        *(float4*)&xs [0][srow + 192][sc] = gx3;
        *(float4*)&wsh[0][srow      ][sc] = gw0;
    }
    __syncthreads();

    for (int s = 0; s < nstep; ++s) {
        const int p = s & 1;
        const bool more = (s + 1 < nstep);
        float4 gx0, gx1, gx2, gx3, gw0;
        if (more) {   // issue next-tile global loads BEFORE compute (latency hides under FMAs)
            const int k0 = kbase + (s + 1) * BK;
            gx0 = *(const float4*)&x[(size_t)(tb+srow      )*DIM + k0 + sc];
            gx1 = *(const float4*)&x[(size_t)(tb+srow +  64)*DIM + k0 + sc];
            gx2 = *(const float4*)&x[(size_t)(tb+srow + 128)*DIM + k0 + sc];
            gx3 = *(const float4*)&x[(size_t)(tb+srow + 192)*DIM + k0 + sc];
            gw0 = *(const float4*)&W[(size_t)srow*DIM + k0 + sc];
        }

#pragma unroll
        for (int kq = 0; kq < 4; ++kq) {
            float4 xv[8], wv[8];
#pragma unroll
            for (int i = 0; i < 8; ++i)
                xv[i] = *(const float4*)&xs [p][tr + 32*i][kq << 2];
#pragma unroll
            for (int j = 0; j < 8; ++j)
                wv[j] = *(const float4*)&wsh[p][er +  8*j][kq << 2];
#pragma unroll
            for (int i = 0; i < 8; ++i)
#pragma unroll
                for (int j = 0; j < 8; ++j) {
                    acc[i][j] = fmaf(xv[i].x, wv[j].x, acc[i][j]);
                    acc[i][j] = fmaf(xv[i].y, wv[j].y, acc[i][j]);
                    acc[i][j] = fmaf(xv[i].z, wv[j].z, acc[i][j]);
                    acc[i][j] = fmaf(xv[i].w, wv[j].w, acc[i][j]);
                }
        }

        if (more) {
            const int q = p ^ 1;
            *(float4*)&xs [q][srow      ][sc] = gx0;
            *(float4*)&xs [q][srow +  64][sc] = gx1;
            *(float4*)&xs [q][srow + 128][sc] = gx2;
            *(float4*)&xs [q][srow + 192][sc] = gx3;
            *(float4*)&wsh[q][srow      ][sc] = gw0;
        }
        __syncthreads();
    }

    // ---- write partials: part[ks][t][e] ----
    float* pp = part + (size_t)ks * TOKENS * NEXP;
#pragma unroll
    for (int i = 0; i < 8; ++i) {
        const int t = tb + tr + 32*i;
#pragma unroll
        for (int j = 0; j < 8; ++j)
            pp[(size_t)t * NEXP + er + 8*j] = acc[i][j];
    }
}

// ---------------- finalize: sum partials + bias, softmax, top-2 ----------------
// grid = TOKENS/64, block = 256: 4 lanes per token, 16 experts each (coalesced reads).
__global__ __launch_bounds__(256)
void finalize(const float* __restrict__ part, const float* __restrict__ bias,
              float* __restrict__ out, int ksplit)
{
    const int tid = threadIdx.x;
    const int t   = blockIdx.x * 64 + (tid >> 2);
    const int eq  = tid & 3;                    // expert quarter: e = eq*16 + c

    float sc[16];
#pragma unroll
    for (int c = 0; c < 16; ++c) sc[c] = 0.f;

    for (int s = 0; s < ksplit; ++s) {
        const float* p = part + ((size_t)s * TOKENS + t) * NEXP + eq * 16;
#pragma unroll
        for (int c4 = 0; c4 < 4; ++c4) {
            const float4 v = *(const float4*)(p + c4 * 4);
            sc[c4*4+0] += v.x; sc[c4*4+1] += v.y;
            sc[c4*4+2] += v.z; sc[c4*4+3] += v.w;
        }
    }
#pragma unroll
    for (int c = 0; c < 16; ++c) sc[c] += bias[eq * 16 + c];

    // local top-2 (ascending scan + strict '>' => lowest index wins ties)
    float m1 = -INFINITY, m2 = -INFINITY;
    int   i1 = 0, i2 = 0;
#pragma unroll
    for (int c = 0; c < 16; ++c) {
        const float v = sc[c];
        const int   e = eq * 16 + c;
        if (v > m1)      { m2 = m1; i2 = i1; m1 = v; i1 = e; }
        else if (v > m2) { m2 = v;  i2 = e; }
    }

    // merge across the 4 lanes of this token (xor 1, then 2)
#pragma unroll
    for (int d = 1; d <= 2; d <<= 1) {
        const float om1 = __shfl_xor(m1, d); const int oi1 = __shfl_xor(i1, d);
        const float om2 = __shfl_xor(m2, d); const int oi2 = __shfl_xor(i2, d);
        if (om1 > m1 || (om1 == m1 && oi1 < i1)) { m2 = m1; i2 = i1; m1 = om1; i1 = oi1; }
        else if (om1 > m2 || (om1 == m2 && oi1 < i2)) { m2 = om1; i2 = oi1; }
        if (om2 > m2 || (om2 == m2 && oi2 < i2)) { m2 = om2; i2 = oi2; }
    }

    // softmax denominator (max is m1, shared by all 4 lanes now)
    float ds = 0.f;
#pragma unroll
    for (int c = 0; c < 16; ++c) ds += __expf(sc[c] - m1);
    ds += __shfl_xor(ds, 1);
    ds += __shfl_xor(ds, 2);

    if (eq == 0) {
        const float inv = 1.0f / ds;
        out[2*t + 0] = (float)i1;
        out[2*t + 1] = (float)i2;
        out[2*TOKENS + 2*t + 0] = inv;                    // exp(m1-m1)/ds
        out[2*TOKENS + 2*t + 1] = __expf(m2 - m1) * inv;
    }
}

extern "C" void kernel_launch(void* const* d_in, const int* in_sizes, int n_in,
                              void* d_out, int out_size, void* d_ws, size_t ws_size,
                              hipStream_t stream)
{
    const float* x = (const float*)d_in[0];   // [16384, 4096]
    const float* W = (const float*)d_in[1];   // [64, 4096]
    const float* b = (const float*)d_in[2];   // [64]
    float* out  = (float*)d_out;
    float* part = (float*)d_ws;

    // ksplit chosen by ws capacity (constant across calls -> graph-safe)
    int ksplit = 8;
    while (ksplit > 1 && ws_size < (size_t)ksplit * TOKENS * NEXP * sizeof(float))
        ksplit >>= 1;
    const int nstep = (DIM / ksplit) / BK;

    gemm_partial<<<dim3((TOKENS / BT) * ksplit), dim3(256), 0, stream>>>(x, W, part, nstep);
    finalize   <<<dim3(TOKENS / 64),             dim3(256), 0, stream>>>(part, b, out, ksplit);
}

// Round 4
// 658.310 us; speedup vs baseline: 1.6077x; 1.6077x over previous
//
#include <hip/hip_runtime.h>
#include <math.h>

#define TOKENS 16384
#define DIM    4096
#define NEXP   64
#define BT     256     // tokens per block
#define BK     16      // k per LDS stage
#define LSTR   20      // x LDS row stride (floats): 16B-aligned, spreads rows across bank-quads

// ---------------- GEMM partial: scores[t][e] partial over a K-slice ----------------
// grid = (TOKENS/BT) * ksplit, block = 256.
// x: staged through double-buffered LDS (coalesced). W: 1 MB, L2-resident ->
// fetched per k-quad directly from global into a 2-deep register pipeline
// (keeps the LDS pipe half-empty -> FMA-bound).
__global__ __launch_bounds__(256)
void gemm_partial(const float* __restrict__ x, const float* __restrict__ W,
                  float* __restrict__ part, int nstep)
{
    __shared__ float xs[2][BT][LSTR];          // 40 KB

    const int tid   = threadIdx.x;
    const int tg    = blockIdx.x & 63;         // token group (TOKENS/BT == 64)
    const int ks    = blockIdx.x >> 6;         // K-slice id
    const int tb    = tg * BT;
    const int kbase = ks * nstep * BK;
    const int nquad = nstep * 4;

    // x staging map: 64 rows x 4 float4 per sweep (coalesced 64B/row across 4 lanes)
    const int srow = tid >> 2;                 // 0..63
    const int scol = (tid & 3) << 2;           // 0,4,8,12

    // compute map: 32 token-threads x 8 expert-threads; 8x8 register tile
    const int tr = tid >> 3;                   // 0..31 -> tokens tr+32i
    const int er = tid & 7;                    // 0..7  -> experts er+8j

    const float* wrow[8];
#pragma unroll
    for (int j = 0; j < 8; ++j) wrow[j] = W + (size_t)(er + 8 * j) * DIM;

    float acc[8][8];
#pragma unroll
    for (int i = 0; i < 8; ++i)
#pragma unroll
        for (int j = 0; j < 8; ++j) acc[i][j] = 0.f;

    float4 wq[2][8];                           // W k-quad double buffer (64 VGPRs)

    // ---- prologue: stage x step 0, prefetch W quad 0 ----
#pragma unroll
    for (int u = 0; u < 4; ++u) {
        const float4 g = *(const float4*)&x[(size_t)(tb + srow + 64*u) * DIM + kbase + scol];
        *(float4*)&xs[0][srow + 64*u][scol] = g;
    }
#pragma unroll
    for (int j = 0; j < 8; ++j) wq[0][j] = *(const float4*)&wrow[j][kbase];
    __syncthreads();

    for (int s = 0; s < nstep; ++s) {
        const int p = s & 1;
        const bool more = (s + 1 < nstep);

        float4 gx[4];
        if (more) {                            // next x step: issue early, land after compute
            const int k0 = kbase + (s + 1) * BK;
#pragma unroll
            for (int u = 0; u < 4; ++u)
                gx[u] = *(const float4*)&x[(size_t)(tb + srow + 64*u) * DIM + k0 + scol];
        }

#pragma unroll
        for (int kq = 0; kq < 4; ++kq) {
            const int cur = kq & 1, nxt = cur ^ 1;

            // prefetch next W k-quad from L2 (clamped dummy at the very end: stays in-bounds)
            const int q  = s * 4 + kq + 1;
            const int kn = (q < nquad) ? kbase + q * 4 : kbase;
#pragma unroll
            for (int j = 0; j < 8; ++j)
                wq[nxt][j] = *(const float4*)&wrow[j][kn];

            float4 xv[8];
#pragma unroll
            for (int i = 0; i < 8; ++i)
                xv[i] = *(const float4*)&xs[p][tr + 32*i][kq << 2];

#pragma unroll
            for (int i = 0; i < 8; ++i)
#pragma unroll
                for (int j = 0; j < 8; ++j) {
                    acc[i][j] = fmaf(xv[i].x, wq[cur][j].x, acc[i][j]);
                    acc[i][j] = fmaf(xv[i].y, wq[cur][j].y, acc[i][j]);
                    acc[i][j] = fmaf(xv[i].z, wq[cur][j].z, acc[i][j]);
                    acc[i][j] = fmaf(xv[i].w, wq[cur][j].w, acc[i][j]);
                }
        }

        if (more) {
            const int b = p ^ 1;
#pragma unroll
            for (int u = 0; u < 4; ++u)
                *(float4*)&xs[b][srow + 64*u][scol] = gx[u];
        }
        __syncthreads();
    }

    // ---- write partials: part[ks][t][e] ----
    float* pp = part + (size_t)ks * TOKENS * NEXP;
#pragma unroll
    for (int i = 0; i < 8; ++i) {
        const int t = tb + tr + 32*i;
#pragma unroll
        for (int j = 0; j < 8; ++j)
            pp[(size_t)t * NEXP + er + 8*j] = acc[i][j];
    }
}

// ---------------- finalize: sum partials + bias, softmax, top-2 ----------------
// grid = TOKENS/64, block = 256: 4 lanes per token, 16 experts each (coalesced).
__global__ __launch_bounds__(256)
void finalize(const float* __restrict__ part, const float* __restrict__ bias,
              float* __restrict__ out, int ksplit)
{
    const int tid = threadIdx.x;
    const int t   = blockIdx.x * 64 + (tid >> 2);
    const int eq  = tid & 3;                   // expert quarter: e = eq*16 + c

    float sc[16];
#pragma unroll
    for (int c = 0; c < 16; ++c) sc[c] = 0.f;

    for (int s = 0; s < ksplit; ++s) {
        const float* p = part + ((size_t)s * TOKENS + t) * NEXP + eq * 16;
#pragma unroll
        for (int c4 = 0; c4 < 4; ++c4) {
            const float4 v = *(const float4*)(p + c4 * 4);
            sc[c4*4+0] += v.x; sc[c4*4+1] += v.y;
            sc[c4*4+2] += v.z; sc[c4*4+3] += v.w;
        }
    }
#pragma unroll
    for (int c = 0; c < 16; ++c) sc[c] += bias[eq * 16 + c];

    // local top-2 (strict '>' ascending scan => lowest index wins ties, matches lax.top_k)
    float m1 = -INFINITY, m2 = -INFINITY;
    int   i1 = 0, i2 = 0;
#pragma unroll
    for (int c = 0; c < 16; ++c) {
        const float v = sc[c];
        const int   e = eq * 16 + c;
        if (v > m1)      { m2 = m1; i2 = i1; m1 = v; i1 = e; }
        else if (v > m2) { m2 = v;  i2 = e; }
    }

    // merge across the 4 lanes of this token
#pragma unroll
    for (int d = 1; d <= 2; d <<= 1) {
        const float om1 = __shfl_xor(m1, d); const int oi1 = __shfl_xor(i1, d);
        const float om2 = __shfl_xor(m2, d); const int oi2 = __shfl_xor(i2, d);
        if (om1 > m1 || (om1 == m1 && oi1 < i1)) { m2 = m1; i2 = i1; m1 = om1; i1 = oi1; }
        else if (om1 > m2 || (om1 == m2 && oi1 < i2)) { m2 = om1; i2 = oi1; }
        if (om2 > m2 || (om2 == m2 && oi2 < i2)) { m2 = om2; i2 = oi2; }
    }

    float ds = 0.f;
#pragma unroll
    for (int c = 0; c < 16; ++c) ds += __expf(sc[c] - m1);
    ds += __shfl_xor(ds, 1);
    ds += __shfl_xor(ds, 2);

    if (eq == 0) {
        const float inv = 1.0f / ds;
        out[2*t + 0] = (float)i1;
        out[2*t + 1] = (float)i2;
        out[2*TOKENS + 2*t + 0] = inv;                 // exp(m1-m1)/ds
        out[2*TOKENS + 2*t + 1] = __expf(m2 - m1) * inv;
    }
}

extern "C" void kernel_launch(void* const* d_in, const int* in_sizes, int n_in,
                              void* d_out, int out_size, void* d_ws, size_t ws_size,
                              hipStream_t stream)
{
    const float* x = (const float*)d_in[0];   // [16384, 4096]
    const float* W = (const float*)d_in[1];   // [64, 4096]
    const float* b = (const float*)d_in[2];   // [64]
    float* out  = (float*)d_out;
    float* part = (float*)d_ws;

    // ksplit limited by ws capacity (constant across calls -> graph-safe)
    int ksplit = 8;
    while (ksplit > 1 && ws_size < (size_t)ksplit * TOKENS * NEXP * sizeof(float))
        ksplit >>= 1;
    const int nstep = (DIM / ksplit) / BK;

    gemm_partial<<<dim3((TOKENS / BT) * ksplit), dim3(256), 0, stream>>>(x, W, part, nstep);
    finalize   <<<dim3(TOKENS / 64),             dim3(256), 0, stream>>>(part, b, out, ksplit);
}